// Round 1
// baseline (419.985 us; speedup 1.0000x reference)
//
#include <hip/hip_runtime.h>
#include <hip/hip_bf16.h>
#include <math.h>

// ---- problem constants (match reference) ----
constexpr int BATCH = 32;
constexpr int LEN   = 240000;
constexpr int HOPS  = 160;
constexpr int T     = 1501;    // LEN/HOP + 1
constexpr int TOUT  = 1504;    // padded to multiple of 8
constexpr int NMEL  = 80;
constexpr int NBIN  = 257;
constexpr int NFFT  = 512;
constexpr float PRE      = 0.97f;
constexpr float LOG_EPS  = 5.9604644775390625e-08f;  // 2^-24
constexpr float STD_EPS  = 1e-5f;
constexpr float BLANK_V  = 27.0f;

constexpr size_t LOGMEL_ELTS = (size_t)BATCH * NMEL * T;  // 3,842,560 floats

// ---------------------------------------------------------------------------
// Kernel 0: column-sparse decomposition of the mel filterbank.
// Each FFT bin f has nonzero weight in at most 2 (consecutive) mel rows:
// triangular filter m covers (mel_f[m], mel_f[m+2]); consecutive intervals
// overlap pairwise only. Store (m0,w0) and (m1,w1) per bin (-1 = absent).
// ---------------------------------------------------------------------------
__global__ __launch_bounds__(256) void k_colinfo(const float* __restrict__ fb,
                                                 int* __restrict__ ma, int* __restrict__ mb,
                                                 float* __restrict__ wa, float* __restrict__ wb) {
  int f = blockIdx.x * blockDim.x + threadIdx.x;
  if (f >= NBIN) return;
  int a = -1, b = -1;
  float va = 0.f, vb = 0.f;
  for (int m = 0; m < NMEL; ++m) {
    float w = fb[m * NBIN + f];
    if (w != 0.f) {
      if (a < 0) { a = m; va = w; }
      else       { b = m; vb = w; }
    }
  }
  ma[f] = a; mb[f] = b; wa[f] = va; wb[f] = vb;
}

// ---------------------------------------------------------------------------
// Kernel 1: one 256-thread block per frame.
// preemph + reflect-pad + Hann window on the fly, radix-2 DIT FFT-512 in LDS,
// power spectrum, sparse mel projection via LDS atomics, log, store.
// ---------------------------------------------------------------------------
__global__ __launch_bounds__(256) void k_logmel(const float* __restrict__ x,
                                                const int* __restrict__ ma, const int* __restrict__ mb,
                                                const float* __restrict__ wa, const float* __restrict__ wb,
                                                float* __restrict__ logmel) {
  __shared__ float re[NFFT], im[NFFT];
  __shared__ float twr[NFFT / 2], twi[NFFT / 2];
  __shared__ float mel[NMEL];

  const int tid = threadIdx.x;
  const int bt  = blockIdx.x;
  const int b   = bt / T;
  const int t   = bt % T;

  // twiddle table: tw[k] = exp(-2*pi*i*k/512), k in [0,256)
  {
    float ang = -6.283185307179586f * (float)tid / (float)NFFT;
    twr[tid] = cosf(ang);
    twi[tid] = sinf(ang);
  }
  if (tid < NMEL) mel[tid] = 0.f;

  const float* xb = x + (size_t)b * LEN;
  // load 2 samples/thread: window (zero outside [96,416)), bit-rev store
  for (int n = tid; n < NFFT; n += 256) {
    int p = t * HOPS + n - NFFT / 2;          // index into preemphasized y
    if (p < 0)    p = -p;                     // reflect pad (single reflection)
    if (p >= LEN) p = 2 * LEN - 2 - p;
    float v = (p == 0) ? xb[0] : (xb[p] - PRE * xb[p - 1]);
    float w = 0.f;
    if (n >= 96 && n < 416)
      w = 0.5f - 0.5f * cosf((float)(n - 96) * (6.283185307179586f / 320.0f));
    v *= w;
    int r = (int)(__brev((unsigned)n) >> 23); // 9-bit reverse
    re[r] = v;
    im[r] = 0.f;
  }
  __syncthreads();

  // radix-2 DIT: 9 stages, one butterfly per thread, disjoint pairs
  int tstep = NFFT / 2;                       // 512/len
  for (int half = 1; half < NFFT; half <<= 1) {
    int maskh = half - 1;
    int pos = tid & maskh;
    int i0  = ((tid & ~maskh) << 1) | pos;
    int i1  = i0 + half;
    int ti_ = pos * tstep;
    float wr = twr[ti_], wi = twi[ti_];
    float br = re[i1], bi = im[i1];
    float tr = br * wr - bi * wi;
    float tq = br * wi + bi * wr;
    float ar = re[i0], ai = im[i0];
    re[i0] = ar + tr; im[i0] = ai + tq;
    re[i1] = ar - tr; im[i1] = ai - tq;
    tstep >>= 1;
    __syncthreads();
  }

  // power -> sparse mel accumulate (<=2 rows per bin)
  for (int k = tid; k < NBIN; k += 256) {
    float rr = re[k], ii = im[k];
    float p = rr * rr + ii * ii;
    int a = ma[k];
    if (a >= 0) atomicAdd(&mel[a], p * wa[k]);
    int bb = mb[k];
    if (bb >= 0) atomicAdd(&mel[bb], p * wb[k]);
  }
  __syncthreads();

  if (tid < NMEL)
    logmel[((size_t)b * NMEL + tid) * T + t] = logf(mel[tid] + LOG_EPS);
}

// ---------------------------------------------------------------------------
// Kernel 2: one block per (b,m) row. Masked two-pass mean/var, normalize,
// zero invalid frames, BLANK pad to 1504. Also writes seq_len (as f32).
// ---------------------------------------------------------------------------
__global__ __launch_bounds__(256) void k_norm(const float* __restrict__ logmel,
                                              const int* __restrict__ xn32,
                                              float* __restrict__ out,
                                              float* __restrict__ outseq) {
  const int bm = blockIdx.x;
  const int b  = bm / NMEL;
  const int m  = bm % NMEL;
  __shared__ float sred[4];
  __shared__ float sbc[2];

  const float* row = logmel + (size_t)bm * T;

  // robust int32/int64 read of xn: real lengths >= 160001, so xn32[1]==0
  // iff the buffer holds int64 (low/high word pairs, little-endian).
  int n;
  {
    int probe = xn32[1];
    int v = (probe == 0) ? xn32[2 * b] : xn32[b];
    n = v / HOPS + 1;
  }

  const int lane = threadIdx.x & 63, wid = threadIdx.x >> 6;

  // pass 1: mean over t < n
  float s = 0.f;
  for (int i = threadIdx.x; i < n; i += 256) s += row[i];
  for (int off = 32; off > 0; off >>= 1) s += __shfl_down(s, off, 64);
  if (lane == 0) sred[wid] = s;
  __syncthreads();
  if (threadIdx.x == 0)
    sbc[0] = (sred[0] + sred[1] + sred[2] + sred[3]) / (float)n;
  __syncthreads();
  const float mean = sbc[0];

  // pass 2: variance (n-1 divisor)
  float s2 = 0.f;
  for (int i = threadIdx.x; i < n; i += 256) {
    float d = row[i] - mean;
    s2 += d * d;
  }
  for (int off = 32; off > 0; off >>= 1) s2 += __shfl_down(s2, off, 64);
  __syncthreads();  // protect sred reuse
  if (lane == 0) sred[wid] = s2;
  __syncthreads();
  if (threadIdx.x == 0) {
    float var = (sred[0] + sred[1] + sred[2] + sred[3]) / (float)(n - 1);
    sbc[1] = sqrtf(var) + STD_EPS;
  }
  __syncthreads();
  const float stdv = sbc[1];

  float* orow = out + (size_t)bm * TOUT;
  for (int i = threadIdx.x; i < TOUT; i += 256) {
    float o;
    if (i < n)      o = (row[i] - mean) / stdv;
    else if (i < T) o = 0.f;
    else            o = BLANK_V;
    orow[i] = o;
  }
  if (m == 0 && threadIdx.x == 0) outseq[b] = (float)n;
}

// ---------------------------------------------------------------------------
extern "C" void kernel_launch(void* const* d_in, const int* in_sizes, int n_in,
                              void* d_out, int out_size, void* d_ws, size_t ws_size,
                              hipStream_t stream) {
  const float* x  = (const float*)d_in[0];
  const int*   xn = (const int*)d_in[1];
  const float* fb = (const float*)d_in[2];

  float* out    = (float*)d_out;
  float* outseq = out + (size_t)BATCH * NMEL * TOUT;  // seq_len tail (32 floats)

  // workspace layout: logmel (15.4 MB) then colinfo arrays
  float* logmel = (float*)d_ws;
  int*   ma = (int*)((char*)d_ws + LOGMEL_ELTS * sizeof(float));
  int*   mb = ma + NBIN;
  float* wa = (float*)(mb + NBIN);
  float* wb = wa + NBIN;

  k_colinfo<<<2, 256, 0, stream>>>(fb, ma, mb, wa, wb);
  k_logmel<<<BATCH * T, 256, 0, stream>>>(x, ma, mb, wa, wb, logmel);
  k_norm<<<BATCH * NMEL, 256, 0, stream>>>(logmel, xn, out, outseq);
}

// Round 2
// 392.080 us; speedup vs baseline: 1.0712x; 1.0712x over previous
//
#include <hip/hip_runtime.h>
#include <math.h>

// ---- problem constants ----
constexpr int BATCH = 32;
constexpr int LEN   = 240000;
constexpr int HOPS  = 160;
constexpr int T     = 1501;    // LEN/HOP + 1
constexpr int TOUT  = 1504;    // padded to 8
constexpr int NMEL  = 80;
constexpr int NBIN  = 257;
constexpr int PAIRS = 751;     // ceil(T/2); frame pair (2q, 2q+1) per wave
constexpr float PRE     = 0.97f;
constexpr float LOG_EPS = 5.9604644775390625e-08f;  // 2^-24
constexpr float STD_EPS = 1e-5f;
constexpr float BLANK_V = 27.0f;

constexpr size_t LOGMEL_ELTS = (size_t)BATCH * T * NMEL;  // [b][t][m] layout

struct cpx { float r, i; };
__device__ __forceinline__ cpx cmul(cpx a, cpx b){ return {a.r*b.r - a.i*b.i, a.r*b.i + a.i*b.r}; }
__device__ __forceinline__ cpx cadd(cpx a, cpx b){ return {a.r+b.r, a.i+b.i}; }
__device__ __forceinline__ cpx csub(cpx a, cpx b){ return {a.r-b.r, a.i-b.i}; }

// in-place 8-point DFT: a[p] = sum_n a[n] W_8^{np}
__device__ __forceinline__ void dft8(cpx* a) {
  const float s = 0.70710678118654752f;
  cpx b0 = cadd(a[0],a[4]), b1 = cadd(a[1],a[5]), b2 = cadd(a[2],a[6]), b3 = cadd(a[3],a[7]);
  cpx t0 = csub(a[0],a[4]), t1 = csub(a[1],a[5]), t2 = csub(a[2],a[6]), t3 = csub(a[3],a[7]);
  cpx e0 = t0;
  cpx e1 = { s*(t1.r + t1.i), s*(t1.i - t1.r) };   // * (s,-s)
  cpx e2 = { t2.i, -t2.r };                         // * -i
  cpx e3 = { s*(t3.i - t3.r), -s*(t3.r + t3.i) };   // * (-s,-s)
  cpx c0 = cadd(b0,b2), c1 = cadd(b1,b3), c2 = csub(b0,b2), c3 = csub(b1,b3);
  cpx f0 = cadd(e0,e2), f1 = cadd(e1,e3), f2 = csub(e0,e2), f3 = csub(e1,e3);
  a[0] = cadd(c0,c1); a[4] = csub(c0,c1);
  a[2] = { c2.r + c3.i, c2.i - c3.r }; a[6] = { c2.r - c3.i, c2.i + c3.r };
  a[1] = cadd(f0,f1); a[5] = csub(f0,f1);
  a[3] = { f2.r + f3.i, f2.i - f3.r }; a[7] = { f2.r - f3.i, f2.i + f3.r };
}

// ---------------------------------------------------------------------------
// mel filterbank column sparsity: each bin feeds <=2 consecutive mel rows
// ---------------------------------------------------------------------------
__global__ __launch_bounds__(256) void k_prep(const float* __restrict__ fb,
                                              int* __restrict__ ma, int* __restrict__ mb,
                                              float* __restrict__ wa, float* __restrict__ wb) {
  int f = blockIdx.x * blockDim.x + threadIdx.x;
  if (f >= NBIN) return;
  int a = -1, b = -1; float va = 0.f, vb = 0.f;
  for (int m = 0; m < NMEL; ++m) {
    float w = fb[m * NBIN + f];
    if (w != 0.f) { if (a < 0) { a = m; va = w; } else { b = m; vb = w; } }
  }
  ma[f] = a; mb[f] = b; wa[f] = va; wb[f] = vb;
}

// ---------------------------------------------------------------------------
// One wave = one FFT-512 of TWO packed real frames (t0=2q re, t0+1 im).
// Radix-8 DIF, registers + 2 swizzled LDS transposes, wave-synchronous
// (no barriers; 4 independent waves per block).
// ---------------------------------------------------------------------------
__global__ __launch_bounds__(256) void k_logmel(const float* __restrict__ x,
    const int* __restrict__ ma, const int* __restrict__ mb,
    const float* __restrict__ wa, const float* __restrict__ wb,
    float* __restrict__ logmel) {
  __shared__ float lds[4 * 1184];
  const int wid = threadIdx.x >> 6;
  const int l   = threadIdx.x & 63;
  float* Tre = lds + wid * 1184;
  float* Tim = Tre + 512;
  float* mel = Tim + 512;                 // mel0[80] ++ mel1[80]

  const int pair = blockIdx.x * 4 + wid;  // grid sized so pair < 32*751
  const int b  = pair / PAIRS;
  const int q  = pair % PAIRS;
  const int t0 = 2 * q;
  const float* xb = x + (size_t)b * LEN;

  mel[l] = 0.f; mel[l + 64] = 0.f;
  if (l < 32) mel[l + 128] = 0.f;

  // ---- build z[n] = win[n] * (y[p0] + i*y[p1]), lane l holds n = l+64j ----
  cpx a[8];
  #pragma unroll
  for (int j = 0; j < 8; ++j) {
    int n = l + 64 * j;
    cpx z = {0.f, 0.f};
    if (n >= 96 && n < 416) {             // window support (WIN=320 centered)
      float w = 0.5f - 0.5f * __cosf((float)(n - 96) * (6.283185307179586f / 320.f));
      int p0 = t0 * HOPS + n - 256;
      int p1 = p0 + HOPS;
      int q0 = p0 < 0 ? -p0 : (p0 >= LEN ? 2 * LEN - 2 - p0 : p0);
      int q1 = p1 < 0 ? -p1 : (p1 >= LEN ? 2 * LEN - 2 - p1 : p1);
      float y0 = (q0 == 0) ? xb[0] : (xb[q0] - PRE * xb[q0 - 1]);
      float y1 = (q1 == 0) ? xb[0] : (xb[q1] - PRE * xb[q1 - 1]);
      z.r = w * y0; z.i = w * y1;
    }
    a[j] = z;
  }

  // ---- stage A: radix-8 over n2 (stride 64), twiddle W_512^{l*p} ----
  dft8(a);
  {
    float sv, cv; __sincosf(-6.283185307179586f * (float)l / 512.f, &sv, &cv);
    cpx w1 = {cv, sv}, cur = w1;
    #pragma unroll
    for (int p = 1; p < 8; ++p) { a[p] = cmul(a[p], cur); cur = cmul(cur, w1); }
  }
  // transpose 1: store v_p[l] at 64p + (l ^ 8p)   (2-way max -> free)
  #pragma unroll
  for (int p = 0; p < 8; ++p) { int idx = 64 * p + (l ^ (8 * p)); Tre[idx] = a[p].r; Tim[idx] = a[p].i; }
  __builtin_amdgcn_wave_barrier();

  const int ph = l >> 3, lo = l & 7;      // lane = (p, m1) for stage B
  #pragma unroll
  for (int m2 = 0; m2 < 8; ++m2) {
    int idx = 64 * ph + ((lo + 8 * m2) ^ (8 * ph));
    a[m2] = {Tre[idx], Tim[idx]};
  }
  // ---- stage B: radix-8 over m2, twiddle W_64^{m1*r} ----
  dft8(a);
  {
    float sv, cv; __sincosf(-6.283185307179586f * (float)lo / 64.f, &sv, &cv);
    cpx w1 = {cv, sv}, cur = w1;
    #pragma unroll
    for (int r = 1; r < 8; ++r) { a[r] = cmul(a[r], cur); cur = cmul(cur, w1); }
  }
  __builtin_amdgcn_wave_barrier();
  // transpose 2: store y(p,m1,r) at 64p + 8*(r^p) + (m1^p)  (2-way -> free)
  #pragma unroll
  for (int r = 0; r < 8; ++r) { int idx = 64 * ph + 8 * (r ^ ph) + (lo ^ ph); Tre[idx] = a[r].r; Tim[idx] = a[r].i; }
  __builtin_amdgcn_wave_barrier();
  // lane = (p, r=lo): gather over m1
  #pragma unroll
  for (int m1 = 0; m1 < 8; ++m1) {
    int idx = 64 * ph + 8 * (lo ^ ph) + (m1 ^ ph);
    a[m1] = {Tre[idx], Tim[idx]};
  }
  // ---- stage C: radix-8 over m1, no twiddle; a[s] = Z[ph + 8*lo + 64*s] ----
  dft8(a);
  __builtin_amdgcn_wave_barrier();
  #pragma unroll
  for (int s = 0; s < 8; ++s) { int k = ph + 8 * lo + 64 * s; Tre[k] = a[s].r; Tim[k] = a[s].i; }
  __builtin_amdgcn_wave_barrier();

  // ---- conjugate-symmetric unpack -> power of both frames -> sparse mel ----
  #pragma unroll
  for (int c = 0; c < 4; ++c) {
    int k  = l + 64 * c;
    int km = (512 - k) & 511;
    float zr = Tre[k], zi = Tim[k], mr = Tre[km], mi = Tim[km];
    float f0r = 0.5f * (zr + mr), f0i = 0.5f * (zi - mi);
    float f1r = 0.5f * (zi + mi), f1i = 0.5f * (mr - zr);
    float p0 = f0r * f0r + f0i * f0i;
    float p1 = f1r * f1r + f1i * f1i;
    int A = ma[k]; float WA = wa[k];
    int B = mb[k]; float WB = wb[k];
    if (A >= 0) { atomicAdd(&mel[A], p0 * WA); atomicAdd(&mel[80 + A], p1 * WA); }
    if (B >= 0) { atomicAdd(&mel[B], p0 * WB); atomicAdd(&mel[80 + B], p1 * WB); }
  }
  if (l == 0) {  // bin 256 (Nyquist): Z[256] -> F0=re, F1=im
    float zr = Tre[256], zi = Tim[256];
    float p0 = zr * zr, p1 = zi * zi;
    int A = ma[256]; float WA = wa[256];
    int B = mb[256]; float WB = wb[256];
    if (A >= 0) { atomicAdd(&mel[A], p0 * WA); atomicAdd(&mel[80 + A], p1 * WA); }
    if (B >= 0) { atomicAdd(&mel[B], p0 * WB); atomicAdd(&mel[80 + B], p1 * WB); }
  }
  __builtin_amdgcn_wave_barrier();

  // ---- log + contiguous [b][t][m] writes ----
  size_t base0 = ((size_t)b * T + t0) * NMEL;
  logmel[base0 + l] = __logf(mel[l] + LOG_EPS);
  if (l < 16) logmel[base0 + 64 + l] = __logf(mel[64 + l] + LOG_EPS);
  if (t0 + 1 < T) {
    size_t base1 = base0 + NMEL;
    logmel[base1 + l] = __logf(mel[80 + l] + LOG_EPS);
    if (l < 16) logmel[base1 + 64 + l] = __logf(mel[144 + l] + LOG_EPS);
  }
}

// ---------------------------------------------------------------------------
// per-(b,m) masked mean / 1/std in ONE pass over [b][t][m] (coalesced)
// ---------------------------------------------------------------------------
__global__ __launch_bounds__(256) void k_stats(const float* __restrict__ logmel,
    const int* __restrict__ xn32, float* __restrict__ stats, float* __restrict__ outseq) {
  const int b = blockIdx.x;
  __shared__ float red[480];
  const int tid = threadIdx.x;
  int n;
  { int probe = xn32[1]; int v = (probe == 0) ? xn32[2 * b] : xn32[b]; n = v / HOPS + 1; }
  float s = 0.f, s2 = 0.f;
  if (tid < 240) {
    const float* base = logmel + (size_t)b * T * NMEL;
    const int tot = n * NMEL;
    for (int e = tid; e < tot; e += 240) { float v = base[e]; s += v; s2 += v * v; }
    red[tid] = s; red[240 + tid] = s2;
  }
  __syncthreads();
  if (tid < 80) {
    float S  = red[tid] + red[80 + tid] + red[160 + tid];
    float S2 = red[240 + tid] + red[320 + tid] + red[400 + tid];
    float fn = (float)n;
    float mean = S / fn;
    float var  = (S2 - fn * mean * mean) / (fn - 1.f);
    var = var < 0.f ? 0.f : var;
    stats[b * 160 + tid]      = mean;
    stats[b * 160 + 80 + tid] = 1.f / (sqrtf(var) + STD_EPS);
  }
  if (tid == 0) outseq[b] = (float)n;
}

// ---------------------------------------------------------------------------
// normalize + transpose [b][t][m] -> out[b][m][t] via LDS tile; BLANK pad
// ---------------------------------------------------------------------------
__global__ __launch_bounds__(256) void k_apply(const float* __restrict__ logmel,
    const float* __restrict__ stats, const int* __restrict__ xn32,
    float* __restrict__ out) {
  const int bid = blockIdx.x;
  const int b = bid / 47, c = bid % 47;
  const int tbase = c * 32;
  __shared__ float tile[32][81];
  __shared__ float smean[80], sistd[80];
  const int tid = threadIdx.x;
  int n;
  { int probe = xn32[1]; int v = (probe == 0) ? xn32[2 * b] : xn32[b]; n = v / HOPS + 1; }
  if (tid < 80) { smean[tid] = stats[b * 160 + tid]; sistd[tid] = stats[b * 160 + 80 + tid]; }
  __syncthreads();
  for (int e = tid; e < 2560; e += 256) {
    int tt = e / 80, m = e % 80;
    int t = tbase + tt;
    float v;
    if (t >= T)      v = BLANK_V;
    else if (t >= n) v = 0.f;
    else             v = (logmel[((size_t)b * T + t) * NMEL + m] - smean[m]) * sistd[m];
    tile[tt][m] = v;
  }
  __syncthreads();
  for (int e = tid; e < 2560; e += 256) {
    int m = e >> 5, tt = e & 31;
    out[((size_t)b * NMEL + m) * TOUT + tbase + tt] = tile[tt][m];
  }
}

// ---------------------------------------------------------------------------
extern "C" void kernel_launch(void* const* d_in, const int* in_sizes, int n_in,
                              void* d_out, int out_size, void* d_ws, size_t ws_size,
                              hipStream_t stream) {
  const float* x  = (const float*)d_in[0];
  const int*   xn = (const int*)d_in[1];
  const float* fb = (const float*)d_in[2];

  float* out    = (float*)d_out;
  float* outseq = out + (size_t)BATCH * NMEL * TOUT;

  float* logmel = (float*)d_ws;
  int*   ma = (int*)((char*)d_ws + LOGMEL_ELTS * sizeof(float));
  int*   mb = ma + NBIN;
  float* wa = (float*)(mb + NBIN);
  float* wb = wa + NBIN;
  float* stats = wb + NBIN;   // 32*160 floats

  k_prep<<<2, 256, 0, stream>>>(fb, ma, mb, wa, wb);
  k_logmel<<<(BATCH * PAIRS) / 4, 256, 0, stream>>>(x, ma, mb, wa, wb, logmel);
  k_stats<<<BATCH, 256, 0, stream>>>(logmel, xn, stats, outseq);
  k_apply<<<BATCH * 47, 256, 0, stream>>>(logmel, stats, xn, out);
}

// Round 3
// 163.997 us; speedup vs baseline: 2.5609x; 2.3908x over previous
//
#include <hip/hip_runtime.h>
#include <math.h>

// ---- problem constants ----
constexpr int BATCH = 32;
constexpr int LEN   = 240000;
constexpr int HOPS  = 160;
constexpr int T     = 1501;    // LEN/HOP + 1
constexpr int TOUT  = 1504;    // padded to 8
constexpr int NMEL  = 80;
constexpr int NBIN  = 257;
constexpr int PAIRS = 751;     // ceil(T/2)
constexpr int NNZ_MAX = 640;   // mel CSR capacity (true nnz <= 514)
constexpr float PRE     = 0.97f;
constexpr float LOG_EPS = 5.9604644775390625e-08f;  // 2^-24
constexpr float STD_EPS = 1e-5f;
constexpr float BLANK_V = 27.0f;

constexpr size_t LOGMEL_ELTS = (size_t)BATCH * T * NMEL;  // [b][t][m]

struct cpx { float r, i; };
__device__ __forceinline__ cpx cmul(cpx a, cpx b){ return {a.r*b.r - a.i*b.i, a.r*b.i + a.i*b.r}; }
__device__ __forceinline__ cpx cadd(cpx a, cpx b){ return {a.r+b.r, a.i+b.i}; }
__device__ __forceinline__ cpx csub(cpx a, cpx b){ return {a.r-b.r, a.i-b.i}; }

__device__ __forceinline__ void dft8(cpx* a) {
  const float s = 0.70710678118654752f;
  cpx b0 = cadd(a[0],a[4]), b1 = cadd(a[1],a[5]), b2 = cadd(a[2],a[6]), b3 = cadd(a[3],a[7]);
  cpx t0 = csub(a[0],a[4]), t1 = csub(a[1],a[5]), t2 = csub(a[2],a[6]), t3 = csub(a[3],a[7]);
  cpx e0 = t0;
  cpx e1 = { s*(t1.r + t1.i), s*(t1.i - t1.r) };
  cpx e2 = { t2.i, -t2.r };
  cpx e3 = { s*(t3.i - t3.r), -s*(t3.r + t3.i) };
  cpx c0 = cadd(b0,b2), c1 = cadd(b1,b3), c2 = csub(b0,b2), c3 = csub(b1,b3);
  cpx f0 = cadd(e0,e2), f1 = cadd(e1,e3), f2 = csub(e0,e2), f3 = csub(e1,e3);
  a[0] = cadd(c0,c1); a[4] = csub(c0,c1);
  a[2] = { c2.r + c3.i, c2.i - c3.r }; a[6] = { c2.r - c3.i, c2.i + c3.r };
  a[1] = cadd(f0,f1); a[5] = csub(f0,f1);
  a[3] = { f2.r + f3.i, f2.i - f3.r }; a[7] = { f2.r - f3.i, f2.i + f3.r };
}

// ---------------------------------------------------------------------------
// CSR of the mel filterbank by ROW: each row m has contiguous bin support
// [lo_m, lo_m+cnt_m). Outputs: lc[m]=lo|(cnt<<16), rsg[m]=row start in wcsr.
// ---------------------------------------------------------------------------
__global__ __launch_bounds__(128) void k_prep(const float* __restrict__ fb,
                                              int* __restrict__ lc, int* __restrict__ rsg,
                                              float* __restrict__ wcsr) {
  __shared__ int cnt_s[80];
  __shared__ int rs_s[81];
  const int m = threadIdx.x;
  int lo = 0, cnt = 0;
  if (m < 80) {
    int first = -1, last = -1;
    for (int f = 0; f < NBIN; ++f)
      if (fb[m * NBIN + f] != 0.f) { if (first < 0) first = f; last = f; }
    if (first >= 0) { lo = first; cnt = last - first + 1; }
    cnt_s[m] = cnt;
  }
  __syncthreads();
  if (threadIdx.x == 0) {
    int a = 0;
    for (int i = 0; i < 80; ++i) { rs_s[i] = a; a += cnt_s[i]; }
    rs_s[80] = a;
  }
  __syncthreads();
  if (m < 80) {
    int r = rs_s[m];
    lc[m]  = lo | (cnt << 16);
    rsg[m] = r;
    for (int j = 0; j < cnt; ++j) wcsr[r + j] = fb[m * NBIN + lo + j];
  }
}

// ---------------------------------------------------------------------------
// One wave = FFT-512 of TWO packed real frames. Radix-8, 2 swizzled LDS
// transposes, wave-synchronous. Mel via CSR (no atomics), power in-place.
// Per-block: Hann window + CSR tables staged once (one __syncthreads).
// ---------------------------------------------------------------------------
__global__ __launch_bounds__(256) void k_logmel(const float* __restrict__ x,
    const int* __restrict__ lc, const int* __restrict__ rsg,
    const float* __restrict__ wcsr, float* __restrict__ logmel) {
  __shared__ float shw[512];
  __shared__ float swc[NNZ_MAX];
  __shared__ int   slc[80];
  __shared__ int   srs[80];
  __shared__ float W[4][1024];

  const int tid = threadIdx.x;
  const int wid = tid >> 6;
  const int l   = tid & 63;

  // ---- block-level staging (shared by all 4 waves) ----
  for (int i = tid; i < 512; i += 256) {
    float w = 0.f;
    if (i >= 96 && i < 416)
      w = 0.5f - 0.5f * __cosf((float)(i - 96) * (6.283185307179586f / 320.f));
    shw[i] = w;
  }
  for (int i = tid; i < NNZ_MAX; i += 256) swc[i] = wcsr[i];
  if (tid < 80) { slc[tid] = lc[tid]; srs[tid] = rsg[tid]; }
  __syncthreads();

  float* Tre = W[wid];
  float* Tim = Tre + 512;   // must stay contiguous: CSR uses Tre + 512*f

  const int pair = blockIdx.x * 4 + wid;       // < 32*751 exactly
  const int b  = pair / PAIRS;
  const int q  = pair % PAIRS;
  const int t0 = 2 * q;
  const float* xb = x + (size_t)b * LEN;

  // ---- cooperative preemph+reflect staging: ys[i] = y(s0-1+i), i<481 ----
  // y(p): q=reflect(p); y = (q==0) ? x[0] : x[q]-PRE*x[q-1]
  const int s0m1 = t0 * HOPS - 161;
  for (int i = l; i < 481; i += 64) {
    int p = s0m1 + i;
    int qq = p < 0 ? -p : (p >= LEN ? 2 * LEN - 2 - p : p);
    Tre[i] = (qq == 0) ? xb[0] : (xb[qq] - PRE * xb[qq - 1]);
  }
  __builtin_amdgcn_wave_barrier();

  // ---- build z[n] = win[n]*(y0 + i*y1), lane l holds n = l+64j ----
  cpx a[8];
  #pragma unroll
  for (int j = 0; j < 8; ++j) {
    int n = l + 64 * j;
    cpx z = {0.f, 0.f};
    if (n >= 96 && n < 416) {
      float w  = shw[n];
      float y0 = Tre[n - 95];
      float y1 = Tre[n + 65];
      z.r = w * y0; z.i = w * y1;
    }
    a[j] = z;
  }
  __builtin_amdgcn_wave_barrier();   // all staged reads precede T1 writes

  // ---- stage A: radix-8 over stride 64, twiddle W_512^{l*p} ----
  dft8(a);
  {
    float sv, cv; __sincosf(-6.283185307179586f * (float)l / 512.f, &sv, &cv);
    cpx w1 = {cv, sv}, cur = w1;
    #pragma unroll
    for (int p = 1; p < 8; ++p) { a[p] = cmul(a[p], cur); cur = cmul(cur, w1); }
  }
  #pragma unroll
  for (int p = 0; p < 8; ++p) { int idx = 64 * p + (l ^ (8 * p)); Tre[idx] = a[p].r; Tim[idx] = a[p].i; }
  __builtin_amdgcn_wave_barrier();

  const int ph = l >> 3, lo8 = l & 7;
  #pragma unroll
  for (int m2 = 0; m2 < 8; ++m2) {
    int idx = 64 * ph + ((lo8 + 8 * m2) ^ (8 * ph));
    a[m2] = {Tre[idx], Tim[idx]};
  }
  // ---- stage B ----
  dft8(a);
  {
    float sv, cv; __sincosf(-6.283185307179586f * (float)lo8 / 64.f, &sv, &cv);
    cpx w1 = {cv, sv}, cur = w1;
    #pragma unroll
    for (int r = 1; r < 8; ++r) { a[r] = cmul(a[r], cur); cur = cmul(cur, w1); }
  }
  __builtin_amdgcn_wave_barrier();
  #pragma unroll
  for (int r = 0; r < 8; ++r) { int idx = 64 * ph + 8 * (r ^ ph) + (lo8 ^ ph); Tre[idx] = a[r].r; Tim[idx] = a[r].i; }
  __builtin_amdgcn_wave_barrier();
  #pragma unroll
  for (int m1 = 0; m1 < 8; ++m1) {
    int idx = 64 * ph + 8 * (lo8 ^ ph) + (m1 ^ ph);
    a[m1] = {Tre[idx], Tim[idx]};
  }
  // ---- stage C + natural-order deposit ----
  dft8(a);
  __builtin_amdgcn_wave_barrier();
  #pragma unroll
  for (int s = 0; s < 8; ++s) { int k = ph + 8 * lo8 + 64 * s; Tre[k] = a[s].r; Tim[k] = a[s].i; }
  __builtin_amdgcn_wave_barrier();

  // ---- conj-symmetric unpack -> power IN PLACE: Tre[k]=p0, Tim[k]=p1 ----
  // primary k in [0,255] owned by exactly one (lane,c); mirrors >=257 never written
  #pragma unroll
  for (int c = 0; c < 4; ++c) {
    int k  = l + 64 * c;
    int km = (512 - k) & 511;
    float zr = Tre[k], zi = Tim[k], mr = Tre[km], mi = Tim[km];
    float f0r = 0.5f * (zr + mr), f0i = 0.5f * (zi - mi);
    float f1r = 0.5f * (zi + mi), f1i = 0.5f * (mr - zr);
    Tre[k] = f0r * f0r + f0i * f0i;
    Tim[k] = f1r * f1r + f1i * f1i;
  }
  if (l == 0) {   // Nyquist bin 256: F0=Z.re, F1=Z.im
    float zr = Tre[256], zi = Tim[256];
    Tre[256] = zr * zr;
    Tim[256] = zi * zi;
  }
  __builtin_amdgcn_wave_barrier();

  // ---- CSR mel: task tau = l+64i -> frame f=tau/80, row m=tau%80 ----
  size_t base0 = ((size_t)b * T + t0) * NMEL;
  #pragma unroll
  for (int i = 0; i < 3; ++i) {
    int tau = l + 64 * i;
    if (tau < 160) {
      int f = (tau >= 80) ? 1 : 0;
      int m = tau - 80 * f;
      int meta = slc[m];
      int lo  = meta & 0xffff;
      int cnt = meta >> 16;
      int pbase = 512 * f + lo;
      int rsm = srs[m];
      float acc = 0.f;
      for (int j = 0; j < cnt; ++j)
        acc += Tre[pbase + j] * swc[rsm + j];
      int t = t0 + f;
      if (t < T)
        logmel[base0 + (size_t)f * NMEL + m] = __logf(acc + LOG_EPS);
    }
  }
}

// ---------------------------------------------------------------------------
// stats stage 1: grid = 32 batches x 8 time-chunks; per-(b,m) partial S/S2
// ---------------------------------------------------------------------------
__global__ __launch_bounds__(256) void k_stats1(const float* __restrict__ logmel,
    const int* __restrict__ xn32, float* __restrict__ ps) {
  const int bc = blockIdx.x;
  const int b = bc >> 3, c = bc & 7;
  __shared__ float red[480];
  const int tid = threadIdx.x;
  int n;
  { int probe = xn32[1]; int v = (probe == 0) ? xn32[2 * b] : xn32[b]; n = v / HOPS + 1; }
  if (tid < 240) {
    const float* base = logmel + (size_t)b * T * NMEL;
    float s = 0.f, s2 = 0.f;
    const int e1 = min(n, (c + 1) * 188) * NMEL;
    for (int e = c * 15040 + tid; e < e1; e += 240) {  // step 240 keeps m = tid%80
      float v = base[e]; s += v; s2 += v * v;
    }
    red[tid] = s; red[240 + tid] = s2;
  }
  __syncthreads();
  if (tid < 80) {
    ps[bc * 160 + tid]      = red[tid] + red[80 + tid] + red[160 + tid];
    ps[bc * 160 + 80 + tid] = red[240 + tid] + red[320 + tid] + red[400 + tid];
  }
}

// stats stage 2: combine 8 chunks -> mean, 1/std; write seq_len
__global__ __launch_bounds__(128) void k_stats2(const float* __restrict__ ps,
    const int* __restrict__ xn32, float* __restrict__ stats, float* __restrict__ outseq) {
  const int b = blockIdx.x;
  const int tid = threadIdx.x;
  int n;
  { int probe = xn32[1]; int v = (probe == 0) ? xn32[2 * b] : xn32[b]; n = v / HOPS + 1; }
  if (tid < 80) {
    float S = 0.f, S2 = 0.f;
    for (int c = 0; c < 8; ++c) {
      S  += ps[(b * 8 + c) * 160 + tid];
      S2 += ps[(b * 8 + c) * 160 + 80 + tid];
    }
    float fn = (float)n;
    float mean = S / fn;
    float var = (S2 - fn * mean * mean) / (fn - 1.f);
    var = var < 0.f ? 0.f : var;
    stats[b * 160 + tid]      = mean;
    stats[b * 160 + 80 + tid] = 1.f / (sqrtf(var) + STD_EPS);
  }
  if (tid == 0) outseq[b] = (float)n;
}

// ---------------------------------------------------------------------------
// normalize + transpose [b][t][m] -> out[b][m][t], float4 both directions
// ---------------------------------------------------------------------------
__global__ __launch_bounds__(256) void k_apply(const float* __restrict__ logmel,
    const float* __restrict__ stats, const int* __restrict__ xn32,
    float* __restrict__ out) {
  const int bid = blockIdx.x;
  const int b = bid / 47, c = bid % 47;
  const int tbase = c * 32;
  __shared__ float tile[32 * 81];
  __shared__ float smean[80], sistd[80];
  const int tid = threadIdx.x;
  int n;
  { int probe = xn32[1]; int v = (probe == 0) ? xn32[2 * b] : xn32[b]; n = v / HOPS + 1; }
  if (tid < 80) { smean[tid] = stats[b * 160 + tid]; sistd[tid] = stats[b * 160 + 80 + tid]; }
  __syncthreads();

  for (int e = tid; e < 640; e += 256) {       // 32 t x 20 float4-of-m
    int tt = e / 20, v = e % 20;
    int t = tbase + tt;
    int m0 = 4 * v;
    float4 val;
    if (t >= T)      val = make_float4(BLANK_V, BLANK_V, BLANK_V, BLANK_V);
    else if (t >= n) val = make_float4(0.f, 0.f, 0.f, 0.f);
    else {
      const float4 g = *(const float4*)&logmel[((size_t)b * T + t) * NMEL + m0];
      val.x = (g.x - smean[m0])     * sistd[m0];
      val.y = (g.y - smean[m0 + 1]) * sistd[m0 + 1];
      val.z = (g.z - smean[m0 + 2]) * sistd[m0 + 2];
      val.w = (g.w - smean[m0 + 3]) * sistd[m0 + 3];
    }
    float* tp = &tile[tt * 81 + m0];
    tp[0] = val.x; tp[1] = val.y; tp[2] = val.z; tp[3] = val.w;
  }
  __syncthreads();
  for (int e = tid; e < 640; e += 256) {       // 80 m x 8 float4-of-t
    int m = e >> 3, v = e & 7;
    int tt0 = 4 * v;
    float4 o;
    o.x = tile[(tt0    ) * 81 + m];
    o.y = tile[(tt0 + 1) * 81 + m];
    o.z = tile[(tt0 + 2) * 81 + m];
    o.w = tile[(tt0 + 3) * 81 + m];
    *(float4*)&out[((size_t)b * NMEL + m) * TOUT + tbase + tt0] = o;
  }
}

// ---------------------------------------------------------------------------
extern "C" void kernel_launch(void* const* d_in, const int* in_sizes, int n_in,
                              void* d_out, int out_size, void* d_ws, size_t ws_size,
                              hipStream_t stream) {
  const float* x  = (const float*)d_in[0];
  const int*   xn = (const int*)d_in[1];
  const float* fb = (const float*)d_in[2];

  float* out    = (float*)d_out;
  float* outseq = out + (size_t)BATCH * NMEL * TOUT;

  float* logmel = (float*)d_ws;
  int*   lc    = (int*)(logmel + LOGMEL_ELTS);
  int*   rsg   = lc + 80;
  float* wcsr  = (float*)(rsg + 80);
  float* stats = wcsr + NNZ_MAX;          // 32*160
  float* ps    = stats + 32 * 160;        // 256*160

  k_prep  <<<1, 128, 0, stream>>>(fb, lc, rsg, wcsr);
  k_logmel<<<(BATCH * PAIRS) / 4, 256, 0, stream>>>(x, lc, rsg, wcsr, logmel);
  k_stats1<<<BATCH * 8, 256, 0, stream>>>(logmel, xn, ps);
  k_stats2<<<BATCH, 128, 0, stream>>>(ps, xn, stats, outseq);
  k_apply <<<BATCH * 47, 256, 0, stream>>>(logmel, stats, xn, out);
}

// Round 4
// 131.289 us; speedup vs baseline: 3.1989x; 1.2491x over previous
//
#include <hip/hip_runtime.h>
#include <math.h>

// ---- problem constants ----
constexpr int BATCH = 32;
constexpr int LEN   = 240000;
constexpr int HOPS  = 160;
constexpr int T     = 1501;    // LEN/HOP + 1
constexpr int TOUT  = 1504;    // padded to 8
constexpr int NMEL  = 80;
constexpr int NBIN  = 257;
constexpr int PAIRS = 751;     // ceil(T/2); one wave = frames (2q, 2q+1)
constexpr int CMAX  = 20;      // max bins per mel row (true max = 18)
constexpr int WSTR  = 25;      // LDS weight stride, coprime with 32 banks
constexpr int P1OFF = 520;     // frame-1 power base in Tre (bank dephase +8)
constexpr float PRE     = 0.97f;
constexpr float LOG_EPS = 5.9604644775390625e-08f;  // 2^-24
constexpr float STD_EPS = 1e-5f;
constexpr float BLANK_V = 27.0f;

constexpr size_t LOGMEL_ELTS = (size_t)BATCH * T * NMEL;  // [b][t][m]

struct cpx { float r, i; };
__device__ __forceinline__ cpx cmul(cpx a, cpx b){ return {a.r*b.r - a.i*b.i, a.r*b.i + a.i*b.r}; }
__device__ __forceinline__ cpx cadd(cpx a, cpx b){ return {a.r+b.r, a.i+b.i}; }
__device__ __forceinline__ cpx csub(cpx a, cpx b){ return {a.r-b.r, a.i-b.i}; }

__device__ __forceinline__ void dft8(cpx* a) {
  const float s = 0.70710678118654752f;
  cpx b0 = cadd(a[0],a[4]), b1 = cadd(a[1],a[5]), b2 = cadd(a[2],a[6]), b3 = cadd(a[3],a[7]);
  cpx t0 = csub(a[0],a[4]), t1 = csub(a[1],a[5]), t2 = csub(a[2],a[6]), t3 = csub(a[3],a[7]);
  cpx e0 = t0;
  cpx e1 = { s*(t1.r + t1.i), s*(t1.i - t1.r) };
  cpx e2 = { t2.i, -t2.r };
  cpx e3 = { s*(t3.i - t3.r), -s*(t3.r + t3.i) };
  cpx c0 = cadd(b0,b2), c1 = cadd(b1,b3), c2 = csub(b0,b2), c3 = csub(b1,b3);
  cpx f0 = cadd(e0,e2), f1 = cadd(e1,e3), f2 = csub(e0,e2), f3 = csub(e1,e3);
  a[0] = cadd(c0,c1); a[4] = csub(c0,c1);
  a[2] = { c2.r + c3.i, c2.i - c3.r }; a[6] = { c2.r - c3.i, c2.i + c3.r };
  a[1] = cadd(f0,f1); a[5] = csub(f0,f1);
  a[3] = { f2.r + f3.i, f2.i - f3.r }; a[7] = { f2.r - f3.i, f2.i + f3.r };
}

__device__ __forceinline__ int read_n(const int* xn32, int b) {
  // xn declared int64 but may land as int32; real lengths >=160001 so the
  // high word of element 0 (int64 case) is 0, while int32 elem 1 is >=160000.
  int probe = xn32[1];
  int v = (probe == 0) ? xn32[2 * b] : xn32[b];
  return v / HOPS + 1;
}

// ---------------------------------------------------------------------------
// k_prep: one block per mel row. Ballot-scan the row's contiguous support,
// write lo|cnt and fixed-stride zero-padded weights. Also zeroes ps[5120].
// ---------------------------------------------------------------------------
__global__ __launch_bounds__(64) void k_prep(const float* __restrict__ fb,
                                             int* __restrict__ lc,
                                             float* __restrict__ wg,
                                             float* __restrict__ ps) {
  const int m = blockIdx.x;
  const int l = threadIdx.x;
  ps[m * 64 + l] = 0.f;                       // 80*64 = 5120 accumulators
  int first = 1 << 20, last = -1;
  for (int it = 0; it < 5; ++it) {
    int f = it * 64 + l;
    float w = (f < NBIN) ? fb[m * NBIN + f] : 0.f;
    unsigned long long mk = __ballot(w != 0.f);
    if (mk) {
      int lo = __ffsll(mk) - 1;
      int hi = 63 - __clzll(mk);
      if (first > NBIN) first = it * 64 + lo;
      last = it * 64 + hi;
    }
  }
  int cnt = (last >= first) ? last - first + 1 : 0;
  if (cnt > CMAX) cnt = CMAX;
  if (first > NBIN) first = 0;
  if (l == 0) lc[m] = first | (cnt << 16);
  if (l < CMAX) wg[m * CMAX + l] = (l < cnt) ? fb[m * NBIN + first + l] : 0.f;
}

// ---------------------------------------------------------------------------
// k_logmel: one wave = FFT-512 of frames (2q,2q+1) packed re/im. Radix-8,
// swizzled LDS transposes, wave-synchronous. CSR mel (fixed 20-unroll,
// stride-25 weights). Per-block masked S/S2 reduction -> global atomics.
// ---------------------------------------------------------------------------
__global__ __launch_bounds__(256) void k_logmel(const float* __restrict__ x,
    const int* __restrict__ lc, const float* __restrict__ wg,
    const int* __restrict__ xn32,
    float* __restrict__ logmel, float* __restrict__ ps) {
  __shared__ float shw[512];
  __shared__ float swg[NMEL * WSTR];
  __shared__ int   slc[NMEL];
  __shared__ float W[4][1024];
  __shared__ float vbuf[4][160];
  __shared__ int   sbw[4];

  const int tid = threadIdx.x;
  const int wid = tid >> 6;
  const int l   = tid & 63;

  // ---- block tables ----
  for (int i = tid; i < 512; i += 256) {
    float w = 0.f;
    if (i >= 96 && i < 416)
      w = 0.5f - 0.5f * __cosf((float)(i - 96) * (6.283185307179586f / 320.f));
    shw[i] = w;
  }
  for (int i = tid; i < NMEL * CMAX; i += 256)
    swg[(i / CMAX) * WSTR + (i % CMAX)] = wg[i];
  if (tid < NMEL) slc[tid] = lc[tid];
  __syncthreads();

  float* Tre = W[wid];
  float* Tim = Tre + 512;

  const int pair = blockIdx.x * 4 + wid;       // exactly 32*751 pairs
  const int b  = pair / PAIRS;
  const int q  = pair % PAIRS;
  const int t0 = 2 * q;
  const float* xb = x + (size_t)b * LEN;
  const int nb = read_n(xn32, b);

  // ---- build z[n] = win[n]*(y(t0,n) + i*y(t0+1,n)) ----
  cpx a[8];
  const int s0x = t0 * HOPS - 161;             // x index of X[0]
  const bool interior = (s0x >= 0) && (s0x + 480 < LEN);   // wave-uniform
  if (interior) {
    // stage raw x once (coalesced), preemph from LDS
    for (int i = l; i < 481; i += 64) Tre[i] = xb[s0x + i];
    __builtin_amdgcn_wave_barrier();
    #pragma unroll
    for (int j = 0; j < 8; ++j) {
      int n = l + 64 * j;
      cpx z = {0.f, 0.f};
      if (n >= 96 && n < 416) {
        float w = shw[n];
        z.r = w * (Tre[n - 95] - PRE * Tre[n - 96]);
        z.i = w * (Tre[n + 65] - PRE * Tre[n + 64]);
      }
      a[j] = z;
    }
    __builtin_amdgcn_wave_barrier();
  } else {
    // boundary frames (q==0 / q==750): reflect on the y-index, direct loads
    #pragma unroll
    for (int j = 0; j < 8; ++j) {
      int n = l + 64 * j;
      cpx z = {0.f, 0.f};
      if (n >= 96 && n < 416) {
        float w = shw[n];
        int p0 = t0 * HOPS + n - 256;
        int p1 = p0 + HOPS;
        int q0 = p0 < 0 ? -p0 : (p0 >= LEN ? 2 * LEN - 2 - p0 : p0);
        int q1 = p1 < 0 ? -p1 : (p1 >= LEN ? 2 * LEN - 2 - p1 : p1);
        float y0 = (q0 == 0) ? xb[0] : (xb[q0] - PRE * xb[q0 - 1]);
        float y1 = (q1 == 0) ? xb[0] : (xb[q1] - PRE * xb[q1 - 1]);
        z.r = w * y0; z.i = w * y1;
      }
      a[j] = z;
    }
  }

  // ---- stage A: radix-8 over stride 64, twiddle W_512^{l*p} ----
  dft8(a);
  {
    float sv, cv; __sincosf(-6.283185307179586f * (float)l / 512.f, &sv, &cv);
    cpx w1 = {cv, sv}, cur = w1;
    #pragma unroll
    for (int p = 1; p < 8; ++p) { a[p] = cmul(a[p], cur); cur = cmul(cur, w1); }
  }
  #pragma unroll
  for (int p = 0; p < 8; ++p) { int idx = 64 * p + (l ^ (8 * p)); Tre[idx] = a[p].r; Tim[idx] = a[p].i; }
  __builtin_amdgcn_wave_barrier();

  const int ph = l >> 3, lo8 = l & 7;
  #pragma unroll
  for (int m2 = 0; m2 < 8; ++m2) {
    int idx = 64 * ph + ((lo8 + 8 * m2) ^ (8 * ph));
    a[m2] = {Tre[idx], Tim[idx]};
  }
  // ---- stage B ----
  dft8(a);
  {
    float sv, cv; __sincosf(-6.283185307179586f * (float)lo8 / 64.f, &sv, &cv);
    cpx w1 = {cv, sv}, cur = w1;
    #pragma unroll
    for (int r = 1; r < 8; ++r) { a[r] = cmul(a[r], cur); cur = cmul(cur, w1); }
  }
  __builtin_amdgcn_wave_barrier();
  #pragma unroll
  for (int r = 0; r < 8; ++r) { int idx = 64 * ph + 8 * (r ^ ph) + (lo8 ^ ph); Tre[idx] = a[r].r; Tim[idx] = a[r].i; }
  __builtin_amdgcn_wave_barrier();
  #pragma unroll
  for (int m1 = 0; m1 < 8; ++m1) {
    int idx = 64 * ph + 8 * (lo8 ^ ph) + (m1 ^ ph);
    a[m1] = {Tre[idx], Tim[idx]};
  }
  // ---- stage C + natural-order deposit ----
  dft8(a);
  __builtin_amdgcn_wave_barrier();
  #pragma unroll
  for (int s = 0; s < 8; ++s) { int k = ph + 8 * lo8 + 64 * s; Tre[k] = a[s].r; Tim[k] = a[s].i; }
  __builtin_amdgcn_wave_barrier();

  // ---- conj-symmetric unpack to REGISTERS, then deposit dephased powers ----
  float P0[4], P1[4];
  #pragma unroll
  for (int c = 0; c < 4; ++c) {
    int k  = l + 64 * c;
    int km = (512 - k) & 511;
    float zr = Tre[k], zi = Tim[k], mr = Tre[km], mi = Tim[km];
    float f0r = 0.5f * (zr + mr), f0i = 0.5f * (zi - mi);
    float f1r = 0.5f * (zi + mi), f1i = 0.5f * (mr - zr);
    P0[c] = f0r * f0r + f0i * f0i;
    P1[c] = f1r * f1r + f1i * f1i;
  }
  float pN0 = 0.f, pN1 = 0.f;
  if (l == 0) { float zr = Tre[256], zi = Tim[256]; pN0 = zr * zr; pN1 = zi * zi; }
  __builtin_amdgcn_wave_barrier();
  #pragma unroll
  for (int c = 0; c < 4; ++c) { int k = l + 64 * c; Tre[k] = P0[c]; Tre[P1OFF + k] = P1[c]; }
  if (l == 0) { Tre[256] = pN0; Tre[P1OFF + 256] = pN1; }
  __builtin_amdgcn_wave_barrier();

  // ---- CSR mel rows: fixed 20-unroll, zero-padded weights ----
  auto melrow = [&](int f, int m) -> float {
    int meta = slc[m];
    int lo = meta & 0xffff;
    const float* pw = &swg[m * WSTR];
    const float* pp = &Tre[(f ? P1OFF : 0) + lo];
    float acc = 0.f;
    #pragma unroll
    for (int j = 0; j < CMAX; ++j) acc += pp[j] * pw[j];
    return __logf(acc + LOG_EPS);
  };

  size_t base0 = ((size_t)b * T + t0) * NMEL;
  { // sec0: frame 0, m = l  (t0 <= 1500 < T always)
    float lv = melrow(0, l);
    logmel[base0 + l] = lv;
    vbuf[wid][l] = (t0 < nb) ? lv : 0.f;
  }
  { // sec1: frame 1, m = l  (skip wave-uniformly when t0+1 == T)
    bool ok = (t0 + 1) < T;
    float lv = ok ? melrow(1, l) : 0.f;
    if (ok) logmel[base0 + NMEL + l] = lv;
    vbuf[wid][80 + l] = (ok && (t0 + 1) < nb) ? lv : 0.f;
  }
  if (l < 32) { // sec2: rows 64..79 of both frames
    int f = l >> 4, m = 64 + (l & 15);
    bool ok = (t0 + f) < T;
    float lv = ok ? melrow(f, m) : 0.f;
    if (ok) logmel[base0 + (size_t)f * NMEL + m] = lv;
    vbuf[wid][f * 80 + m] = (ok && (t0 + f) < nb) ? lv : 0.f;
  }
  if (l == 0) sbw[wid] = b;
  __syncthreads();

  // ---- block reduce -> global atomics (handles batch-straddling blocks) ----
  if (tid < NMEL) {
    const int b0 = (blockIdx.x * 4) / PAIRS;
    const bool strad = ((blockIdx.x * 4 + 3) / PAIRS) != b0;
    float s0 = 0.f, q0 = 0.f, s1 = 0.f, q1 = 0.f;
    #pragma unroll
    for (int w = 0; w < 4; ++w) {
      float v0 = vbuf[w][tid], v1 = vbuf[w][80 + tid];
      if (sbw[w] == b0) { s0 += v0 + v1; q0 += v0 * v0 + v1 * v1; }
      else              { s1 += v0 + v1; q1 += v0 * v0 + v1 * v1; }
    }
    atomicAdd(&ps[b0 * 160 + tid], s0);
    atomicAdd(&ps[b0 * 160 + 80 + tid], q0);
    if (strad) {
      atomicAdd(&ps[(b0 + 1) * 160 + tid], s1);
      atomicAdd(&ps[(b0 + 1) * 160 + 80 + tid], q1);
    }
  }
}

// ---------------------------------------------------------------------------
// k_apply: finalize stats from ps, normalize + transpose to out[b][m][t],
// zero invalid, BLANK pad; writes seq_len.
// ---------------------------------------------------------------------------
__global__ __launch_bounds__(256) void k_apply(const float* __restrict__ logmel,
    const float* __restrict__ ps, const int* __restrict__ xn32,
    float* __restrict__ out, float* __restrict__ outseq) {
  const int bid = blockIdx.x;
  const int b = bid / 47, c = bid % 47;
  const int tbase = c * 32;
  __shared__ float tile[32 * 81];
  __shared__ float smean[80], sistd[80];
  const int tid = threadIdx.x;
  const int n = read_n(xn32, b);
  if (tid < 80) {
    float S = ps[b * 160 + tid], S2 = ps[b * 160 + 80 + tid];
    float fn = (float)n;
    float mean = S / fn;
    float var = (S2 - fn * mean * mean) / (fn - 1.f);
    var = var < 0.f ? 0.f : var;
    smean[tid] = mean;
    sistd[tid] = 1.f / (sqrtf(var) + STD_EPS);
  }
  __syncthreads();

  for (int e = tid; e < 640; e += 256) {       // 32 t x 20 float4-of-m
    int tt = e / 20, v = e % 20;
    int t = tbase + tt;
    int m0 = 4 * v;
    float4 val;
    if (t >= T)      val = make_float4(BLANK_V, BLANK_V, BLANK_V, BLANK_V);
    else if (t >= n) val = make_float4(0.f, 0.f, 0.f, 0.f);
    else {
      const float4 g = *(const float4*)&logmel[((size_t)b * T + t) * NMEL + m0];
      val.x = (g.x - smean[m0])     * sistd[m0];
      val.y = (g.y - smean[m0 + 1]) * sistd[m0 + 1];
      val.z = (g.z - smean[m0 + 2]) * sistd[m0 + 2];
      val.w = (g.w - smean[m0 + 3]) * sistd[m0 + 3];
    }
    float* tp = &tile[tt * 81 + m0];
    tp[0] = val.x; tp[1] = val.y; tp[2] = val.z; tp[3] = val.w;
  }
  __syncthreads();
  for (int e = tid; e < 640; e += 256) {       // 80 m x 8 float4-of-t
    int m = e >> 3, v = e & 7;
    int tt0 = 4 * v;
    float4 o;
    o.x = tile[(tt0    ) * 81 + m];
    o.y = tile[(tt0 + 1) * 81 + m];
    o.z = tile[(tt0 + 2) * 81 + m];
    o.w = tile[(tt0 + 3) * 81 + m];
    *(float4*)&out[((size_t)b * NMEL + m) * TOUT + tbase + tt0] = o;
  }
  if (c == 0 && tid == 0) outseq[b] = (float)n;
}

// ---------------------------------------------------------------------------
extern "C" void kernel_launch(void* const* d_in, const int* in_sizes, int n_in,
                              void* d_out, int out_size, void* d_ws, size_t ws_size,
                              hipStream_t stream) {
  const float* x  = (const float*)d_in[0];
  const int*   xn = (const int*)d_in[1];
  const float* fb = (const float*)d_in[2];

  float* out    = (float*)d_out;
  float* outseq = out + (size_t)BATCH * NMEL * TOUT;

  float* logmel = (float*)d_ws;
  int*   lc = (int*)(logmel + LOGMEL_ELTS);
  float* wg = (float*)(lc + NMEL);            // 80*CMAX
  float* ps = wg + NMEL * CMAX;               // 32*160 atomic accumulators

  k_prep  <<<NMEL, 64, 0, stream>>>(fb, lc, wg, ps);
  k_logmel<<<(BATCH * PAIRS) / 4, 256, 0, stream>>>(x, lc, wg, xn, logmel, ps);
  k_apply <<<BATCH * 47, 256, 0, stream>>>(logmel, ps, xn, out, outseq);
}

// Round 5
// 128.261 us; speedup vs baseline: 3.2744x; 1.0236x over previous
//
#include <hip/hip_runtime.h>
#include <math.h>

// ---- problem constants ----
constexpr int BATCH = 32;
constexpr int LEN   = 240000;
constexpr int HOPS  = 160;
constexpr int T     = 1501;    // LEN/HOP + 1
constexpr int TOUT  = 1504;    // padded to 8
constexpr int NMEL  = 80;
constexpr int NBIN  = 257;
constexpr int PAIRS = 751;     // ceil(T/2); one wave = frames (2q, 2q+1)
constexpr int CMAX  = 20;      // max bins per mel row (true max = 18)
constexpr int WSTR  = 21;      // LDS weight stride, coprime with 32 banks
constexpr float PRE     = 0.97f;
constexpr float LOG_EPS = 5.9604644775390625e-08f;  // 2^-24
constexpr float STD_EPS = 1e-5f;
constexpr float BLANK_V = 27.0f;

constexpr size_t LOGMEL_ELTS = (size_t)BATCH * T * NMEL;  // [b][t][m]

typedef __attribute__((ext_vector_type(2))) float v2f;   // (re,im) / (P0,P1)

__device__ __forceinline__ v2f cmul(v2f a, v2f b) {
  v2f r;
  r.x = a.x * b.x - a.y * b.y;
  r.y = a.x * b.y + a.y * b.x;
  return r;
}

// in-place 8-point DFT on packed complex (v_pk_add/sub for the adds)
__device__ __forceinline__ void dft8(v2f* a) {
  const float s = 0.70710678118654752f;
  v2f b0 = a[0] + a[4], b1 = a[1] + a[5], b2 = a[2] + a[6], b3 = a[3] + a[7];
  v2f t0 = a[0] - a[4], t1 = a[1] - a[5], t2 = a[2] - a[6], t3 = a[3] - a[7];
  v2f e0 = t0, e1, e2, e3;
  e1.x = s * (t1.x + t1.y); e1.y = s * (t1.y - t1.x);
  e2.x = t2.y;              e2.y = -t2.x;
  e3.x = s * (t3.y - t3.x); e3.y = -s * (t3.x + t3.y);
  v2f c0 = b0 + b2, c1 = b1 + b3, c2 = b0 - b2, c3 = b1 - b3;
  v2f f0 = e0 + e2, f1 = e1 + e3, f2 = e0 - e2, f3 = e1 - e3;
  a[0] = c0 + c1; a[4] = c0 - c1;
  a[2].x = c2.x + c3.y; a[2].y = c2.y - c3.x;
  a[6].x = c2.x - c3.y; a[6].y = c2.y + c3.x;
  a[1] = f0 + f1; a[5] = f0 - f1;
  a[3].x = f2.x + f3.y; a[3].y = f2.y - f3.x;
  a[7].x = f2.x - f3.y; a[7].y = f2.y + f3.x;
}

__device__ __forceinline__ float hann(int n) {   // n in [96,416)
  return 0.5f - 0.5f * __cosf((float)(n - 96) * (6.283185307179586f / 320.f));
}

__device__ __forceinline__ int read_n(const int* xn32, int b) {
  // xn declared int64 but may land as int32; lengths >=160001 so int64's
  // high word (elem 1) is 0 while int32 elem 1 >= 160000.
  int probe = xn32[1];
  int v = (probe == 0) ? xn32[2 * b] : xn32[b];
  return v / HOPS + 1;
}

// ---------------------------------------------------------------------------
// k_prep: one block per mel row; ballot-scan contiguous support; zero ps.
// ---------------------------------------------------------------------------
__global__ __launch_bounds__(64) void k_prep(const float* __restrict__ fb,
                                             int* __restrict__ lc,
                                             float* __restrict__ wg,
                                             float* __restrict__ ps) {
  const int m = blockIdx.x;
  const int l = threadIdx.x;
  ps[m * 64 + l] = 0.f;                       // 80*64 = 5120 accumulators
  int first = 1 << 20, last = -1;
  for (int it = 0; it < 5; ++it) {
    int f = it * 64 + l;
    float w = (f < NBIN) ? fb[m * NBIN + f] : 0.f;
    unsigned long long mk = __ballot(w != 0.f);
    if (mk) {
      int lo = __ffsll(mk) - 1;
      int hi = 63 - __clzll(mk);
      if (first > NBIN) first = it * 64 + lo;
      last = it * 64 + hi;
    }
  }
  int cnt = (last >= first) ? last - first + 1 : 0;
  if (cnt > CMAX) cnt = CMAX;
  if (first > NBIN) first = 0;
  if (l == 0) lc[m] = first | (cnt << 16);
  if (l < CMAX) wg[m * CMAX + l] = (l < cnt) ? fb[m * NBIN + first + l] : 0.f;
}

// ---------------------------------------------------------------------------
// k_logmel: one wave = FFT-512 of frames (2q,2q+1) packed re/im (v2f math,
// b64 LDS transposes). Packed power -> packed CSR mel (both frames at once).
// Per-block masked S/S2 reduction -> global atomics.
// ---------------------------------------------------------------------------
__global__ __launch_bounds__(256, 6) void k_logmel(const float* __restrict__ x,
    const int* __restrict__ lc, const float* __restrict__ wg,
    const int* __restrict__ xn32,
    float* __restrict__ logmel, float* __restrict__ ps) {
  __shared__ v2f   Wv[4][512];        // 16 KB: FFT workspace / packed power
  __shared__ float swg[NMEL * WSTR];  // 6.72 KB
  __shared__ int   slc[NMEL];
  __shared__ v2f   vbuf[4][NMEL];     // 2.56 KB
  __shared__ int   sbw[4];

  const int tid = threadIdx.x;
  const int wid = tid >> 6;
  const int l   = tid & 63;

  // ---- block tables ----
  for (int i = tid; i < NMEL * CMAX; i += 256)
    swg[(i / CMAX) * WSTR + (i % CMAX)] = wg[i];
  if (tid < NMEL) slc[tid] = lc[tid];
  __syncthreads();

  v2f* Wvw = Wv[wid];

  const int pair = blockIdx.x * 4 + wid;       // exactly 32*751 pairs
  const int b  = pair / PAIRS;
  const int q  = pair % PAIRS;
  const int t0 = 2 * q;
  const float* xb = x + (size_t)b * LEN;
  const int nb = read_n(xn32, b);

  // ---- build z[n] = win[n]*(y(t0,n) + i*y(t0+1,n)) ----
  v2f a[8];
  const int s0x = t0 * HOPS - 161;             // x index of staged[0]
  const bool interior = (s0x >= 0) && (s0x + 480 < LEN);   // wave-uniform
  if (interior) {
    float* Ts = (float*)Wvw;                   // stage raw x once (coalesced)
    for (int i = l; i < 481; i += 64) Ts[i] = xb[s0x + i];
    __builtin_amdgcn_wave_barrier();
    #pragma unroll
    for (int j = 0; j < 8; ++j) {
      int n = l + 64 * j;
      v2f z = {0.f, 0.f};
      if (n >= 96 && n < 416) {
        float w = hann(n);
        v2f y;
        y.x = Ts[n - 95] - PRE * Ts[n - 96];
        y.y = Ts[n + 65] - PRE * Ts[n + 64];
        z = y * w;
      }
      a[j] = z;
    }
    __builtin_amdgcn_wave_barrier();           // staged reads precede T1 writes
  } else {
    // boundary pairs (q==0 / q==750): reflect on the y-index, direct loads
    #pragma unroll
    for (int j = 0; j < 8; ++j) {
      int n = l + 64 * j;
      v2f z = {0.f, 0.f};
      if (n >= 96 && n < 416) {
        float w = hann(n);
        int p0 = t0 * HOPS + n - 256;
        int p1 = p0 + HOPS;
        int q0 = p0 < 0 ? -p0 : (p0 >= LEN ? 2 * LEN - 2 - p0 : p0);
        int q1 = p1 < 0 ? -p1 : (p1 >= LEN ? 2 * LEN - 2 - p1 : p1);
        v2f y;
        y.x = (q0 == 0) ? xb[0] : (xb[q0] - PRE * xb[q0 - 1]);
        y.y = (q1 == 0) ? xb[0] : (xb[q1] - PRE * xb[q1 - 1]);
        z = y * w;
      }
      a[j] = z;
    }
  }

  // ---- stage A: radix-8 over stride 64, twiddle W_512^{l*p} ----
  dft8(a);
  {
    float sv, cv; __sincosf(-6.283185307179586f * (float)l / 512.f, &sv, &cv);
    v2f w1 = {cv, sv}, cur = w1;
    #pragma unroll
    for (int p = 1; p < 8; ++p) { a[p] = cmul(a[p], cur); cur = cmul(cur, w1); }
  }
  #pragma unroll
  for (int p = 0; p < 8; ++p) Wvw[64 * p + (l ^ (8 * p))] = a[p];
  __builtin_amdgcn_wave_barrier();

  const int ph = l >> 3, lo8 = l & 7;
  #pragma unroll
  for (int m2 = 0; m2 < 8; ++m2)
    a[m2] = Wvw[64 * ph + ((lo8 + 8 * m2) ^ (8 * ph))];
  // ---- stage B ----
  dft8(a);
  {
    float sv, cv; __sincosf(-6.283185307179586f * (float)lo8 / 64.f, &sv, &cv);
    v2f w1 = {cv, sv}, cur = w1;
    #pragma unroll
    for (int r = 1; r < 8; ++r) { a[r] = cmul(a[r], cur); cur = cmul(cur, w1); }
  }
  __builtin_amdgcn_wave_barrier();
  #pragma unroll
  for (int r = 0; r < 8; ++r) Wvw[64 * ph + 8 * (r ^ ph) + (lo8 ^ ph)] = a[r];
  __builtin_amdgcn_wave_barrier();
  #pragma unroll
  for (int m1 = 0; m1 < 8; ++m1)
    a[m1] = Wvw[64 * ph + 8 * (lo8 ^ ph) + (m1 ^ ph)];
  // ---- stage C + natural-order deposit ----
  dft8(a);
  __builtin_amdgcn_wave_barrier();
  #pragma unroll
  for (int s = 0; s < 8; ++s) Wvw[ph + 8 * lo8 + 64 * s] = a[s];
  __builtin_amdgcn_wave_barrier();

  // ---- conj-symmetric unpack -> packed power (P0,P1) in place ----
  v2f Ppk[4];
  #pragma unroll
  for (int c = 0; c < 4; ++c) {
    int k  = l + 64 * c;
    int km = (512 - k) & 511;
    v2f z = Wvw[k], mz = Wvw[km];
    float f0r = 0.5f * (z.x + mz.x), f0i = 0.5f * (z.y - mz.y);
    float f1r = 0.5f * (z.y + mz.y), f1i = 0.5f * (mz.x - z.x);
    Ppk[c].x = f0r * f0r + f0i * f0i;
    Ppk[c].y = f1r * f1r + f1i * f1i;
  }
  v2f pN = {0.f, 0.f};
  if (l == 0) { v2f zN = Wvw[256]; pN.x = zN.x * zN.x; pN.y = zN.y * zN.y; }
  __builtin_amdgcn_wave_barrier();
  #pragma unroll
  for (int c = 0; c < 4; ++c) Wvw[l + 64 * c] = Ppk[c];
  if (l == 0) Wvw[256] = pN;
  __builtin_amdgcn_wave_barrier();

  // ---- packed CSR mel: both frames at once (fixed 20-unroll, zero-pad) ----
  auto melpk = [&](int m) -> v2f {
    int lo = slc[m] & 0xffff;
    const float* pw = &swg[m * WSTR];
    const v2f* pp = &Wvw[lo];
    v2f acc = {0.f, 0.f};
    #pragma unroll
    for (int j = 0; j < CMAX; ++j) acc += pp[j] * pw[j];
    return acc;
  };

  const bool ok1 = (t0 + 1) < T;
  size_t base0 = ((size_t)b * T + t0) * NMEL;
  { // rows 0..63: m = l
    v2f acc = melpk(l);
    float lv0 = __logf(acc.x + LOG_EPS);
    float lv1 = __logf(acc.y + LOG_EPS);
    logmel[base0 + l] = lv0;
    if (ok1) logmel[base0 + NMEL + l] = lv1;
    v2f v; v.x = (t0 < nb) ? lv0 : 0.f; v.y = (t0 + 1 < nb) ? lv1 : 0.f;
    vbuf[wid][l] = v;
  }
  if (l < 16) { // rows 64..79
    int m = 64 + l;
    v2f acc = melpk(m);
    float lv0 = __logf(acc.x + LOG_EPS);
    float lv1 = __logf(acc.y + LOG_EPS);
    logmel[base0 + m] = lv0;
    if (ok1) logmel[base0 + NMEL + m] = lv1;
    v2f v; v.x = (t0 < nb) ? lv0 : 0.f; v.y = (t0 + 1 < nb) ? lv1 : 0.f;
    vbuf[wid][m] = v;
  }
  if (l == 0) sbw[wid] = b;
  __syncthreads();

  // ---- block reduce -> global atomics (handles batch-straddling blocks) ----
  if (tid < NMEL) {
    const int b0 = (blockIdx.x * 4) / PAIRS;
    const bool strad = ((blockIdx.x * 4 + 3) / PAIRS) != b0;
    float s0 = 0.f, q0 = 0.f, s1 = 0.f, q1 = 0.f;
    #pragma unroll
    for (int w = 0; w < 4; ++w) {
      v2f v = vbuf[w][tid];
      if (sbw[w] == b0) { s0 += v.x + v.y; q0 += v.x * v.x + v.y * v.y; }
      else              { s1 += v.x + v.y; q1 += v.x * v.x + v.y * v.y; }
    }
    atomicAdd(&ps[b0 * 160 + tid], s0);
    atomicAdd(&ps[b0 * 160 + 80 + tid], q0);
    if (strad) {
      atomicAdd(&ps[(b0 + 1) * 160 + tid], s1);
      atomicAdd(&ps[(b0 + 1) * 160 + 80 + tid], q1);
    }
  }
}

// ---------------------------------------------------------------------------
// k_apply: finalize stats, normalize + transpose [b][t][m] -> out[b][m][t],
// zero invalid, BLANK pad; 64-wide t tiles, float4 both directions.
// ---------------------------------------------------------------------------
__global__ __launch_bounds__(256) void k_apply(const float* __restrict__ logmel,
    const float* __restrict__ ps, const int* __restrict__ xn32,
    float* __restrict__ out, float* __restrict__ outseq) {
  const int bid = blockIdx.x;
  const int b = bid / 24, c = bid % 24;
  const int tbase = c * 64;
  __shared__ float tile[64 * 81];
  __shared__ float smean[80], sistd[80];
  const int tid = threadIdx.x;
  const int n = read_n(xn32, b);
  if (tid < 80) {
    float S = ps[b * 160 + tid], S2 = ps[b * 160 + 80 + tid];
    float fn = (float)n;
    float mean = S / fn;
    float var = (S2 - fn * mean * mean) / (fn - 1.f);
    var = var < 0.f ? 0.f : var;
    smean[tid] = mean;
    sistd[tid] = 1.f / (sqrtf(var) + STD_EPS);
  }
  __syncthreads();

  for (int e = tid; e < 1280; e += 256) {      // 64 t x 20 float4-of-m
    int tt = e / 20, v = e % 20;
    int t = tbase + tt;
    int m0 = 4 * v;
    float4 val;
    if (t >= T)      val = make_float4(BLANK_V, BLANK_V, BLANK_V, BLANK_V);
    else if (t >= n) val = make_float4(0.f, 0.f, 0.f, 0.f);
    else {
      const float4 g = *(const float4*)&logmel[((size_t)b * T + t) * NMEL + m0];
      val.x = (g.x - smean[m0])     * sistd[m0];
      val.y = (g.y - smean[m0 + 1]) * sistd[m0 + 1];
      val.z = (g.z - smean[m0 + 2]) * sistd[m0 + 2];
      val.w = (g.w - smean[m0 + 3]) * sistd[m0 + 3];
    }
    float* tp = &tile[tt * 81 + m0];
    tp[0] = val.x; tp[1] = val.y; tp[2] = val.z; tp[3] = val.w;
  }
  __syncthreads();
  for (int e = tid; e < 1280; e += 256) {      // 80 m x 16 float4-of-t
    int m = e >> 4, v = e & 15;
    int tt0 = 4 * v;
    int t = tbase + tt0;
    if (t < TOUT) {
      float4 o;
      o.x = tile[(tt0    ) * 81 + m];
      o.y = tile[(tt0 + 1) * 81 + m];
      o.z = tile[(tt0 + 2) * 81 + m];
      o.w = tile[(tt0 + 3) * 81 + m];
      *(float4*)&out[((size_t)b * NMEL + m) * TOUT + t] = o;
    }
  }
  if (c == 0 && tid == 0) outseq[b] = (float)n;
}

// ---------------------------------------------------------------------------
extern "C" void kernel_launch(void* const* d_in, const int* in_sizes, int n_in,
                              void* d_out, int out_size, void* d_ws, size_t ws_size,
                              hipStream_t stream) {
  const float* x  = (const float*)d_in[0];
  const int*   xn = (const int*)d_in[1];
  const float* fb = (const float*)d_in[2];

  float* out    = (float*)d_out;
  float* outseq = out + (size_t)BATCH * NMEL * TOUT;

  float* logmel = (float*)d_ws;
  int*   lc = (int*)(logmel + LOGMEL_ELTS);
  float* wg = (float*)(lc + NMEL);            // 80*CMAX
  float* ps = wg + NMEL * CMAX;               // 32*160 atomic accumulators

  k_prep  <<<NMEL, 64, 0, stream>>>(fb, lc, wg, ps);
  k_logmel<<<(BATCH * PAIRS) / 4, 256, 0, stream>>>(x, lc, wg, xn, logmel, ps);
  k_apply <<<BATCH * 24, 256, 0, stream>>>(logmel, ps, xn, out, outseq);
}